// Round 6
// baseline (75.712 us; speedup 1.0000x reference)
//
#include <hip/hip_runtime.h>

// Vanilla tanh RNN scan: B=4096, T=1024, F=H=3.
// Quad layout: 4 lanes/batch (lane j = unit j, lane 3 duplicates unit 2).
// C=2 chains per lane (2 batches per lane) -> the two serial recurrences
// interleave in the issue stream, hiding each other's dependent-chain latency
// (round 5: 111 cyc/step = ~40 issue + ~70 exposed chain latency, VALUBusy 9%).
// All X loads / Y stores are inline asm -> deterministic vmcnt stream,
// hand-counted waits, register double-buffers that hipcc cannot sink
// (rounds 1-3: VGPR_Count 64/124/44 proved compiler-visible prefetch sinks).
// tanh(p) = 1 - 2*rcp(exp2(s*p)+1), s = 2*log2(e) folded into weights;
// recurrence carried on rn = rcp(exp2(z)+1).

static constexpr int BATCH = 4096;
static constexpr int TLEN  = 1024;
static constexpr int ROW   = TLEN * 3;
static constexpr long HN_OFF = (long)BATCH * TLEN * 3;

#define SCL 2.8853900817779268f  // 2*log2(e)

template<int CTRL>
__device__ __forceinline__ float qdpp(float v) {
  int r = __builtin_amdgcn_update_dpp(0, __float_as_int(v), CTRL, 0xF, 0xF, true);
  return __int_as_float(r);
}

#define LOADF4(dst, base, OFF) \
  asm volatile("global_load_dwordx4 %0, %1, off offset:" #OFF \
               : "=v"(dst) : "v"(base) : "memory")

#define STOREF(base, val, OFF) \
  asm volatile("global_store_dword %0, %1, off offset:" #OFF \
               :: "v"(base), "v"(val) : "memory")

#define WAITV(N) asm volatile("s_waitcnt vmcnt(" #N ")" ::: "memory")

// P is a float4[12] array name; all indices compile-time constants.
#define LOADCHUNK(P, PTR) do { \
  LOADF4(P[0], PTR, 0);    LOADF4(P[1], PTR, 16);   LOADF4(P[2], PTR, 32); \
  LOADF4(P[3], PTR, 48);   LOADF4(P[4], PTR, 64);   LOADF4(P[5], PTR, 80); \
  LOADF4(P[6], PTR, 96);   LOADF4(P[7], PTR, 112);  LOADF4(P[8], PTR, 128); \
  LOADF4(P[9], PTR, 144);  LOADF4(P[10], PTR, 160); LOADF4(P[11], PTR, 176); \
} while (0)

// one RNN step for BOTH chains; x*{0,1,2} are the step inputs (registers)
#define STEP2(xa0, xa1, xa2, xb0, xb1, xb2, SB0, SB1, OFF) do { \
  float rA0 = qdpp<0x09>(rn0); float rB0 = qdpp<0x52>(rn0); \
  float rA1 = qdpp<0x09>(rn1); float rB1 = qdpp<0x52>(rn1); \
  float zp0 = fmaf((xa2), wi2, fmaf((xa1), wi1, fmaf((xa0), wi0, cc))); \
  float zp1 = fmaf((xb2), wi2, fmaf((xb1), wi1, fmaf((xb0), wi0, cc))); \
  float z0  = fmaf(rB0, whB, fmaf(rA0, whA, fmaf(rn0, whS, zp0))); \
  float z1  = fmaf(rB1, whB, fmaf(rA1, whA, fmaf(rn1, whS, zp1))); \
  float e0  = __builtin_amdgcn_exp2f(z0); \
  float e1  = __builtin_amdgcn_exp2f(z1); \
  rn0 = __builtin_amdgcn_rcpf(e0 + 1.0f); \
  rn1 = __builtin_amdgcn_rcpf(e1 + 1.0f); \
  float hv0 = fmaf(-2.0f, rn0, 1.0f); \
  float hv1 = fmaf(-2.0f, rn1, 1.0f); \
  STOREF(SB0, hv0, OFF); \
  STOREF(SB1, hv1, OFF); \
} while (0)

#define DOPAIR(P0, P1, SB0, SB1) do { \
  STEP2(P0[0].x,P0[0].y,P0[0].z,  P1[0].x,P1[0].y,P1[0].z,  SB0,SB1, 0); \
  STEP2(P0[0].w,P0[1].x,P0[1].y,  P1[0].w,P1[1].x,P1[1].y,  SB0,SB1, 12); \
  STEP2(P0[1].z,P0[1].w,P0[2].x,  P1[1].z,P1[1].w,P1[2].x,  SB0,SB1, 24); \
  STEP2(P0[2].y,P0[2].z,P0[2].w,  P1[2].y,P1[2].z,P1[2].w,  SB0,SB1, 36); \
  STEP2(P0[3].x,P0[3].y,P0[3].z,  P1[3].x,P1[3].y,P1[3].z,  SB0,SB1, 48); \
  STEP2(P0[3].w,P0[4].x,P0[4].y,  P1[3].w,P1[4].x,P1[4].y,  SB0,SB1, 60); \
  STEP2(P0[4].z,P0[4].w,P0[5].x,  P1[4].z,P1[4].w,P1[5].x,  SB0,SB1, 72); \
  STEP2(P0[5].y,P0[5].z,P0[5].w,  P1[5].y,P1[5].z,P1[5].w,  SB0,SB1, 84); \
  STEP2(P0[6].x,P0[6].y,P0[6].z,  P1[6].x,P1[6].y,P1[6].z,  SB0,SB1, 96); \
  STEP2(P0[6].w,P0[7].x,P0[7].y,  P1[6].w,P1[7].x,P1[7].y,  SB0,SB1, 108); \
  STEP2(P0[7].z,P0[7].w,P0[8].x,  P1[7].z,P1[7].w,P1[8].x,  SB0,SB1, 120); \
  STEP2(P0[8].y,P0[8].z,P0[8].w,  P1[8].y,P1[8].z,P1[8].w,  SB0,SB1, 132); \
  STEP2(P0[9].x,P0[9].y,P0[9].z,  P1[9].x,P1[9].y,P1[9].z,  SB0,SB1, 144); \
  STEP2(P0[9].w,P0[10].x,P0[10].y, P1[9].w,P1[10].x,P1[10].y, SB0,SB1, 156); \
  STEP2(P0[10].z,P0[10].w,P0[11].x, P1[10].z,P1[10].w,P1[11].x, SB0,SB1, 168); \
  STEP2(P0[11].y,P0[11].z,P0[11].w, P1[11].y,P1[11].z,P1[11].w, SB0,SB1, 180); \
} while (0)

__global__ __launch_bounds__(64, 1) void rnn_scan_kernel(
    const float* __restrict__ X, const float* __restrict__ H0,
    const float* __restrict__ Wih, const float* __restrict__ Whh,
    const float* __restrict__ bih, const float* __restrict__ bhh,
    float* __restrict__ out)
{
  const int lane = threadIdx.x;
  const int wb   = blockIdx.x * 32;     // 32 batches per wave (2 per lane)
  const int q    = lane >> 2;           // batch-in-wave (chain 0)
  const int j    = lane & 3;            // unit (3 = duplicate of 2)
  const int jr   = (j < 3) ? j : 2;
  const int ja   = (jr == 2) ? 0 : jr + 1;
  const int jb   = (ja == 2) ? 0 : ja + 1;

  // pre-scaled weights: z = cc + x.wi + rn*whS + rA*whA + rB*whB
  const float wi0 = SCL * Wih[jr*3+0];
  const float wi1 = SCL * Wih[jr*3+1];
  const float wi2 = SCL * Wih[jr*3+2];
  const float whS = -2.0f * SCL * Whh[jr*3+jr];
  const float whA = -2.0f * SCL * Whh[jr*3+ja];
  const float whB = -2.0f * SCL * Whh[jr*3+jb];
  const float cc  = SCL * (bih[jr] + bhh[jr] +
                           Whh[jr*3+0] + Whh[jr*3+1] + Whh[jr*3+2]);

  const int b0 = wb + q;        // chain 0 batch
  const int b1 = wb + 16 + q;   // chain 1 batch

  float rn0 = 0.5f - 0.5f * H0[b0*3 + jr];
  float rn1 = 0.5f - 0.5f * H0[b1*3 + jr];

  const float* Xr0 = X + (size_t)b0 * ROW;
  const float* Xr1 = X + (size_t)b1 * ROW;
  float* Yq0 = out + (size_t)b0 * ROW + jr;
  float* Yq1 = out + (size_t)b1 * ROW + jr;

  float4 A0[12], A1[12], B0[12], B1[12];

  const float* pLa0 = Xr0;       const float* pLa1 = Xr1;        // even chunks
  const float* pLb0 = Xr0 + 48;  const float* pLb1 = Xr1 + 48;   // odd chunks
  LOADCHUNK(A0, pLa0); LOADCHUNK(A1, pLa1); pLa0 += 96; pLa1 += 96;
  LOADCHUNK(B0, pLb0); LOADCHUNK(B1, pLb1); pLb0 += 96; pLb1 += 96;
  float* pSa0 = Yq0;       float* pSa1 = Yq1;
  float* pSb0 = Yq0 + 48;  float* pSb1 = Yq1 + 48;

  for (int k = 0; k < 32; ++k) {
    // even chunk 2k (buffers A*). Need L_A(2k).
    // k==0: newer = L_B(1) 24. steady: newer = st_B(2k-1) 32 + L_B(2k+1) 24 = 56.
    if (k == 0) { WAITV(24); } else { WAITV(56); }
    __builtin_amdgcn_sched_barrier(0);
    DOPAIR(A0, A1, pSa0, pSa1);
    pSa0 += 96; pSa1 += 96;
    if (k < 31) { LOADCHUNK(A0, pLa0); LOADCHUNK(A1, pLa1); pLa0 += 96; pLa1 += 96; }

    // odd chunk 2k+1 (buffers B*). Need L_B(2k+1).
    // steady: newer = st_A(2k) 32 + L_A(2k+2) 24 = 56. k==31: newer = st_A 32.
    if (k == 31) { WAITV(32); } else { WAITV(56); }
    __builtin_amdgcn_sched_barrier(0);
    DOPAIR(B0, B1, pSb0, pSb1);
    pSb0 += 96; pSb1 += 96;
    if (k < 31) { LOADCHUNK(B0, pLb0); LOADCHUNK(B1, pLb1); pLb0 += 96; pLb1 += 96; }
  }

  // final hidden state h_n (lane 3 writes bit-identical duplicate of lane 2)
  out[HN_OFF + (size_t)b0*3 + jr] = fmaf(-2.0f, rn0, 1.0f);
  out[HN_OFF + (size_t)b1*3 + jr] = fmaf(-2.0f, rn1, 1.0f);
}

extern "C" void kernel_launch(void* const* d_in, const int* in_sizes, int n_in,
                              void* d_out, int out_size, void* d_ws, size_t ws_size,
                              hipStream_t stream) {
  const float* X   = (const float*)d_in[0];
  const float* H0  = (const float*)d_in[1];
  const float* Wih = (const float*)d_in[2];
  const float* Whh = (const float*)d_in[3];
  const float* bih = (const float*)d_in[4];
  const float* bhh = (const float*)d_in[5];
  float* out = (float*)d_out;

  dim3 grid(BATCH / 32), block(64);   // 128 waves, 32 batches/wave (C=2)
  hipLaunchKernelGGL(rnn_scan_kernel, grid, block, 0, stream,
                     X, H0, Wih, Whh, bih, bhh, out);
}